// Round 10
// baseline (361.150 us; speedup 1.0000x reference)
//
#include <hip/hip_runtime.h>

#if __has_builtin(__builtin_amdgcn_exp2f)
#define EXP2F(x) __builtin_amdgcn_exp2f(x)
#else
#define EXP2F(x) exp2f(x)
#endif
#if __has_builtin(__builtin_amdgcn_rcpf)
#define RCPF(x) __builtin_amdgcn_rcpf(x)
#else
#define RCPF(x) (1.0f / (x))
#endif

namespace {

constexpr int B_ = 2048, T_ = 512, D_ = 8, H_ = 20, L_ = 10;
constexpr int NG    = 16;        // batch group per block (MFMA N)
constexpr int PADK  = 40;        // bf16 elems per [batch] row (80 B)
constexpr int NW    = 11;        // 10 layer waves + 1 head wave
constexpr int NTHR  = NW * 64;   // 704
constexpr int DEPTH = 4;         // h ring-buffer depth (elastic slack)
constexpr int SLOT_STRIDE  = L_ * NG * PADK;  // 6400 shorts
constexpr int LAYER_STRIDE = NG * PADK;       // 640 shorts

typedef float f32x4 __attribute__((ext_vector_type(4)));
typedef short s16x8 __attribute__((ext_vector_type(8)));   // 8 bf16, 4 VGPRs

#define LD4(p) (*reinterpret_cast<const f32x4*>(p))

// fp32 -> bf16 bits, round-to-nearest-even (matches v_cvt_pk_bf16_f32)
__device__ __forceinline__ unsigned short f2bf(float f) {
    unsigned u = __builtin_bit_cast(unsigned, f);
    return (unsigned short)((u + 0x7FFFu + ((u >> 16) & 1u)) >> 16);
}
__device__ __forceinline__ float bf2f(unsigned short b) {
    return __builtin_bit_cast(float, (unsigned)b << 16);
}
__device__ __forceinline__ unsigned cvt_pk_bf16(float s0, float s1) {
    unsigned r;
    asm("v_cvt_pk_bf16_f32 %0, %1, %2" : "=v"(r) : "v"(s0), "v"(s1));
    return r;
}

__device__ __forceinline__ f32x4 mfma_bf16(s16x8 a, s16x8 b, f32x4 c) {
    return __builtin_amdgcn_mfma_f32_16x16x32_bf16(a, b, c, 0, 0, 0);
}

__device__ __forceinline__ float tanh_fast(float x) {
    float e = EXP2F(x * 2.8853900817779268f);
    return fmaf(-2.0f, RCPF(1.0f + e), 1.0f);
}

// acquire-poll a workgroup progress counter (LDS; lgkmcnt-only fencing)
__device__ __forceinline__ void wait_ge(int* p, int v) {
    while (__hip_atomic_load(p, __ATOMIC_ACQUIRE,
                             __HIP_MEMORY_SCOPE_WORKGROUP) < v) {}
    __builtin_amdgcn_sched_barrier(0);  // no LDS-read motion above the poll
}

// R9 post-mortem: RELEASE at workgroup scope emits s_waitcnt vmcnt(0) --
// wave 0's x prefetch (and the head's out store) got force-drained EVERY
// step (~900cy HBM latency), throttling the whole wave chain. R8's
// __syncthreads had identical drain semantics, which is why R8~=R9.
// Publish needs only LDS ordering: lgkmcnt(0) + RELAXED store.
__device__ __forceinline__ void publish(int* p, int v) {
    asm volatile("s_waitcnt lgkmcnt(0)" ::: "memory");
    __hip_atomic_store(p, v, __ATOMIC_RELAXED, __HIP_MEMORY_SCOPE_WORKGROUP);
}

// SELF-TIMED wavefront (R9 structure): wave w = layer w runs its own t-loop,
// wave 10 = MLP head; prog[] handoff, h ring-buffered DEPTH=4.
// R10 deltas: vmcnt-free publish, 3-deep x prefetch, WAR wait moved after
// the MFMA/tanh (it only gates the h stores).
__global__ __launch_bounds__(NTHR) void rnn_async(
    const float* __restrict__ x,      // [B,T,8]
    const float* __restrict__ w_ih0,  // [20,8]
    const float* __restrict__ w_ih,   // [9,20,20]
    const float* __restrict__ w_hh,   // [10,20,20]
    const float* __restrict__ b_ih,   // [10,20]
    const float* __restrict__ b_hh,   // [10,20]
    const float* __restrict__ fc_w,   // [20,20]
    const float* __restrict__ fc_b,   // [20]
    const float* __restrict__ l2_w,   // [1,20]
    const float* __restrict__ l2_b,   // [1]
    float* __restrict__ out)          // [B,T] flat
{
    __shared__ __align__(16) unsigned short h_lds[DEPTH][L_][NG][PADK]; // 51.2KB
    __shared__ int prog[16];

    const int tid = threadIdx.x;
    const int w   = tid >> 6;       // 0..9 layer wave, 10 head wave
    const int l   = tid & 63;
    const int col = l & 15;         // batch slot (B,D) / row slot (A)
    const int g   = l >> 4;         // k-group (A,B) / row-group (D)
    const int bg  = blockIdx.x * NG;

    // zero all DEPTH slots (h0 = 0; K-pad stays 0) + prog
    {
        uint4* p4 = reinterpret_cast<uint4*>(&h_lds[0][0][0][0]);
        const int n4 = DEPTH * L_ * NG * PADK / 8;  // 3200 uint4
        for (int i = tid; i < n4; i += NTHR) p4[i] = make_uint4(0, 0, 0, 0);
        if (tid < 16) prog[tid] = 0;
    }

    // ---- A fragments (hi/lo split), biases, head constants ----
    s16x8 a0_hi = {0,0,0,0,0,0,0,0}, a0_lo = a0_hi, a1_hi = a0_hi, a1_lo = a0_hi;
    s16x8 h0_hi = a0_hi, h0_lo = a0_hi, h1_hi = a0_hi, h1_lo = a0_hi;
    f32x4 bias0 = {0.f, 0.f, 0.f, 0.f}, bias1 = bias0;
    f32x4 l2v0 = bias0, l2v1 = bias0;
    float l2bv = 0.f;
    const bool mt1ok = col < (H_ - 16);

    if (w < L_) {
        const int layer = w;
        #pragma unroll
        for (int e = 0; e < 8; ++e) {
            const int k = g * 8 + e;
            float wv0 = 0.f, wv1 = 0.f;
            if (layer == 0) {
                if (k < 16) {                 // cols [0..7]=x_hi, [8..15]=x_lo
                    wv0 = w_ih0[col * D_ + (k & 7)];
                    if (mt1ok) wv1 = w_ih0[(16 + col) * D_ + (k & 7)];
                }
            } else if (k < H_) {
                wv0 = w_ih[((layer - 1) * H_ + col) * H_ + k];
                if (mt1ok) wv1 = w_ih[((layer - 1) * H_ + 16 + col) * H_ + k];
            }
            unsigned short b0 = f2bf(wv0), b1 = f2bf(wv1);
            a0_hi[e] = (short)b0; a0_lo[e] = (short)f2bf(wv0 - bf2f(b0));
            a1_hi[e] = (short)b1; a1_lo[e] = (short)f2bf(wv1 - bf2f(b1));
            float uv0 = 0.f, uv1 = 0.f;
            if (k < H_) {
                uv0 = w_hh[(layer * H_ + col) * H_ + k];
                if (mt1ok) uv1 = w_hh[(layer * H_ + 16 + col) * H_ + k];
            }
            unsigned short c0 = f2bf(uv0), c1 = f2bf(uv1);
            h0_hi[e] = (short)c0; h0_lo[e] = (short)f2bf(uv0 - bf2f(c0));
            h1_hi[e] = (short)c1; h1_lo[e] = (short)f2bf(uv1 - bf2f(c1));
        }
        #pragma unroll
        for (int r = 0; r < 4; ++r) {
            const int row = g * 4 + r;
            bias0[r] = b_ih[layer * H_ + row] + b_hh[layer * H_ + row];
            bias1[r] = (g == 0) ? (b_ih[layer * H_ + 16 + r] +
                                   b_hh[layer * H_ + 16 + r]) : 0.f;
        }
    } else {
        #pragma unroll
        for (int e = 0; e < 8; ++e) {
            const int k = g * 8 + e;
            float f0 = 0.f, f1 = 0.f;
            if (k < H_) {
                f0 = fc_w[col * H_ + k];
                if (mt1ok) f1 = fc_w[(16 + col) * H_ + k];
            }
            unsigned short b0 = f2bf(f0), b1 = f2bf(f1);
            a0_hi[e] = (short)b0; a0_lo[e] = (short)f2bf(f0 - bf2f(b0));
            a1_hi[e] = (short)b1; a1_lo[e] = (short)f2bf(f1 - bf2f(b1));
        }
        #pragma unroll
        for (int r = 0; r < 4; ++r) {
            bias0[r] = fc_b[g * 4 + r];
            bias1[r] = (g == 0) ? fc_b[16 + r] : 0.f;
            l2v0[r]  = l2_w[g * 4 + r];
            l2v1[r]  = (g == 0) ? l2_w[16 + r] : 0.f;
        }
        l2bv = l2_b[0];
    }

    // wave-0 x prefetch, 3 deep (use-distance ~3 steps >> HBM latency)
    f32x4 xq0a = {0.f,0.f,0.f,0.f}, xq0b = xq0a;
    f32x4 xq1a = xq0a, xq1b = xq0a, xq2a = xq0a, xq2b = xq0a;
    if (w == 0 && g < 2) {
        const float* xp = x + (size_t)(bg + col) * T_ * D_;
        xq0a = LD4(xp);          xq0b = LD4(xp + 4);
        xq1a = LD4(xp + D_);     xq1b = LD4(xp + D_ + 4);
        xq2a = LD4(xp + 2 * D_); xq2b = LD4(xp + 2 * D_ + 4);
    }

    __syncthreads();  // init + frags visible; ONLY barrier in the kernel

    unsigned short* const hb = &h_lds[0][0][0][0];
    const f32x4 z4 = {0.f, 0.f, 0.f, 0.f};

    if (w < L_) {
        const int rdB1 = w * LAYER_STRIDE + col * PADK + g * 8;
        const int rdB0 = (w ? (w - 1) * LAYER_STRIDE : 0) + col * PADK + g * 8;
        const int wr0  = w * LAYER_STRIDE + col * PADK + g * 4;
        const int wr1  = w * LAYER_STRIDE + col * PADK + 16;
        for (int t = 0; t < T_; ++t) {
            const int s_cur = (t & 3) * SLOT_STRIDE;
            const int s_prv = ((t + 3) & 3) * SLOT_STRIDE;
            // own-h (B1): no cross-wave dependency, issue first
            s16x8 B1 = *reinterpret_cast<const s16x8*>(hb + s_prv + rdB1);
            s16x8 B0;
            if (w == 0) {
                s16x8 xf = {0,0,0,0,0,0,0,0};
                if (g < 2) {
                    #pragma unroll
                    for (int e = 0; e < 8; ++e) {
                        float f = (e < 4) ? xq0a[e] : xq0b[e - 4];
                        unsigned short hbit = f2bf(f);
                        xf[e] = (short)((g == 0) ? hbit : f2bf(f - bf2f(hbit)));
                    }
                    xq0a = xq1a; xq0b = xq1b;
                    xq1a = xq2a; xq1b = xq2b;
                    if (t + 3 < T_) {
                        const float* xp = x + ((size_t)(bg + col) * T_ + t + 3) * D_;
                        xq2a = LD4(xp); xq2b = LD4(xp + 4);
                    }
                }
                B0 = xf;
            } else {
                wait_ge(&prog[w - 1], t + 1);   // RAW: h[w-1][t] published
                B0 = *reinterpret_cast<const s16x8*>(hb + s_cur + rdB0);
            }
            // two parallel 2-deep MFMA chains per accumulator
            f32x4 A  = mfma_bf16(h0_hi, B1, bias0);
            f32x4 Ab = mfma_bf16(h0_lo, B1, z4);
            f32x4 C  = mfma_bf16(h1_hi, B1, bias1);
            f32x4 Cb = mfma_bf16(h1_lo, B1, z4);
            A  = mfma_bf16(a0_hi, B0, A);
            Ab = mfma_bf16(a0_lo, B0, Ab);
            C  = mfma_bf16(a1_hi, B0, C);
            Cb = mfma_bf16(a1_lo, B0, Cb);
            f32x4 acc0 = A + Ab, acc1 = C + Cb;
            uint2 pw;
            pw.x = cvt_pk_bf16(tanh_fast(acc0[0]), tanh_fast(acc0[1]));
            pw.y = cvt_pk_bf16(tanh_fast(acc0[2]), tanh_fast(acc0[3]));
            uint2 qw = make_uint2(0u, 0u);
            if (g == 0) {
                qw.x = cvt_pk_bf16(tanh_fast(acc1[0]), tanh_fast(acc1[1]));
                qw.y = cvt_pk_bf16(tanh_fast(acc1[2]), tanh_fast(acc1[3]));
            }
            // WAR (gates only the stores): consumer w+1 finished step t-4
            if (t >= DEPTH) wait_ge(&prog[w + 1], t - (DEPTH - 1));
            *reinterpret_cast<uint2*>(hb + s_cur + wr0) = pw;
            if (g == 0)
                *reinterpret_cast<uint2*>(hb + s_cur + wr1) = qw;
            if (l == 0) publish(&prog[w], t + 1);
        }
    } else {
        // head wave: y[t] from h[9][t]
        const int rdH = (L_ - 1) * LAYER_STRIDE + col * PADK + g * 8;
        for (int t = 0; t < T_; ++t) {
            wait_ge(&prog[L_ - 1], t + 1);
            s16x8 Bh = *reinterpret_cast<const s16x8*>(
                hb + (t & 3) * SLOT_STRIDE + rdH);
            f32x4 z0  = mfma_bf16(a0_hi, Bh, bias0);
            f32x4 z0b = mfma_bf16(a0_lo, Bh, z4);
            f32x4 z1  = mfma_bf16(a1_hi, Bh, bias1);
            f32x4 z1b = mfma_bf16(a1_lo, Bh, z4);
            z0 += z0b; z1 += z1b;
            float part = 0.f;
            #pragma unroll
            for (int r = 0; r < 4; ++r) {
                part = fmaf(l2v0[r], fmaxf(z0[r], 0.f), part);
                part = fmaf(l2v1[r], fmaxf(z1[r], 0.f), part);
            }
            part += __shfl_xor(part, 16);
            part += __shfl_xor(part, 32);
            if (l < NG) out[(size_t)(bg + l) * T_ + t] = part + l2bv;
            // publish = "Bh read done" (lgkmcnt covers it; out store floats)
            if (l == 0) publish(&prog[L_], t + 1);
        }
    }
}

}  // namespace

extern "C" void kernel_launch(void* const* d_in, const int* in_sizes, int n_in,
                              void* d_out, int out_size, void* d_ws, size_t ws_size,
                              hipStream_t stream) {
    const float* x     = (const float*)d_in[0];
    const float* w_ih0 = (const float*)d_in[1];
    const float* w_ih  = (const float*)d_in[2];
    const float* w_hh  = (const float*)d_in[3];
    const float* b_ih  = (const float*)d_in[4];
    const float* b_hh  = (const float*)d_in[5];
    const float* fc_w  = (const float*)d_in[6];
    const float* fc_b  = (const float*)d_in[7];
    const float* l2_w  = (const float*)d_in[8];
    const float* l2_b  = (const float*)d_in[9];
    float* out = (float*)d_out;

    const int grid = B_ / NG;  // 128
    hipLaunchKernelGGL(rnn_async, dim3(grid), dim3(NTHR), 0, stream,
                       x, w_ih0, w_ih, w_hh, b_ih, b_hh, fc_w, fc_b,
                       l2_w, l2_b, out);
}